// Round 1
// baseline (998.074 us; speedup 1.0000x reference)
//
#include <hip/hip_runtime.h>

#define NNODES 100000
#define NEDGES 6400000
#define NEG_SLOPE 0.2f

// ---------------- init: out = bias, denom = 0 ----------------
__global__ void gat_init(float* __restrict__ out, float* __restrict__ denom,
                         const float* __restrict__ bias, int n) {
    float b0 = bias[0], b1 = bias[1];
    int i = blockIdx.x * blockDim.x + threadIdx.x;
    int stride = gridDim.x * blockDim.x;
    for (; i < n; i += stride) {
        out[2 * i]     = b0;
        out[2 * i + 1] = b1;
        denom[i]       = 0.0f;
    }
}

// ---------------- node pass: h = x @ W, a_src/a_dst scalars ----------------
// One 64-lane wave per node row. Lane l handles features k=2l, 2l+1.
__global__ void gat_node(const float* __restrict__ x, const float* __restrict__ W,
                         const float* __restrict__ att_src, const float* __restrict__ att_dst,
                         float2* __restrict__ h, float* __restrict__ a_src,
                         float* __restrict__ a_dst, int n) {
    int gtid  = blockIdx.x * blockDim.x + threadIdx.x;
    int wave  = gtid >> 6;
    int lane  = threadIdx.x & 63;
    int nwaves = (gridDim.x * blockDim.x) >> 6;

    for (int node = wave; node < n; node += nwaves) {
        // coalesced: wave reads 512 contiguous bytes
        float2 xx = *(const float2*)(x + (size_t)node * 128 + lane * 2);
        // W is [128][2] row-major; k=2l -> W[4l],W[4l+1]; k=2l+1 -> W[4l+2],W[4l+3]
        float2 w0 = *(const float2*)(W + lane * 4);
        float2 w1 = *(const float2*)(W + lane * 4 + 2);
        float c0 = xx.x * w0.x + xx.y * w1.x;
        float c1 = xx.x * w0.y + xx.y * w1.y;
        #pragma unroll
        for (int off = 32; off; off >>= 1) {
            c0 += __shfl_down(c0, off);
            c1 += __shfl_down(c1, off);
        }
        if (lane == 0) {
            h[node] = make_float2(c0, c1);
            a_src[node] = c0 * att_src[0] + c1 * att_src[1];
            a_dst[node] = c0 * att_dst[0] + c1 * att_dst[1];
        }
    }
}

// ---------------- edge pass 1: ex = exp(lrelu(logit)), denom += ex ----------
__global__ void gat_edge1(const int* __restrict__ src, const int* __restrict__ dst,
                          const float* __restrict__ ea,
                          const float* __restrict__ a_src, const float* __restrict__ a_dst,
                          const float* __restrict__ W_edge, const float* __restrict__ att_edge,
                          float* __restrict__ exs, float* __restrict__ denom, int ne) {
    float k = W_edge[0] * att_edge[0] + W_edge[1] * att_edge[1];
    int i = blockIdx.x * blockDim.x + threadIdx.x;
    int stride = gridDim.x * blockDim.x;
    for (; i < ne; i += stride) {
        int s = src[i];
        int d = dst[i];
        float al = a_src[s] + a_dst[d] + k * ea[i];
        al = al > 0.0f ? al : NEG_SLOPE * al;
        float e = __expf(al);
        exs[i] = e;                 // stash in alpha region of d_out
        atomicAdd(&denom[d], e);
    }
}

// ---------------- edge pass 2: normalize + weighted scatter-add -------------
__global__ void gat_edge2(const int* __restrict__ src, const int* __restrict__ dst,
                          const float2* __restrict__ h, const float* __restrict__ denom,
                          float* __restrict__ alpha, float* __restrict__ out, int ne) {
    int i = blockIdx.x * blockDim.x + threadIdx.x;
    int stride = gridDim.x * blockDim.x;
    for (; i < ne; i += stride) {
        int s = src[i];
        int d = dst[i];
        float an = alpha[i] / (denom[d] + 1e-16f);
        alpha[i] = an;              // final alpha output
        float2 hh = h[s];
        atomicAdd(&out[2 * d],     hh.x * an);
        atomicAdd(&out[2 * d + 1], hh.y * an);
    }
}

extern "C" void kernel_launch(void* const* d_in, const int* in_sizes, int n_in,
                              void* d_out, int out_size, void* d_ws, size_t ws_size,
                              hipStream_t stream) {
    const float* x        = (const float*)d_in[0];
    const int*   ei       = (const int*)  d_in[1];
    const float* ea       = (const float*)d_in[2];
    const float* W_src    = (const float*)d_in[3];
    const float* W_edge   = (const float*)d_in[4];
    const float* att_src  = (const float*)d_in[5];
    const float* att_dst  = (const float*)d_in[6];
    const float* att_edge = (const float*)d_in[7];
    const float* bias     = (const float*)d_in[8];

    float* out   = (float*)d_out;            // [N,2] flat
    float* alpha = out + 2 * NNODES;         // [E] flat (ex stash, then alpha_n)

    // workspace: h [N float2] | a_src [N] | a_dst [N] | denom [N]
    float2* h     = (float2*)d_ws;
    float*  a_src = (float*)(h + NNODES);
    float*  a_dst = a_src + NNODES;
    float*  denom = a_dst + NNODES;

    const int* src = ei;            // edge_index[0]
    const int* dst = ei + NEDGES;   // edge_index[1]

    gat_init <<<400, 256, 0, stream>>>(out, denom, bias, NNODES);
    gat_node <<<1024, 256, 0, stream>>>(x, W_src, att_src, att_dst, h, a_src, a_dst, NNODES);
    gat_edge1<<<2048, 256, 0, stream>>>(src, dst, ea, a_src, a_dst, W_edge, att_edge,
                                        alpha, denom, NEDGES);
    gat_edge2<<<2048, 256, 0, stream>>>(src, dst, h, denom, alpha, out, NEDGES);
}